// Round 5
// baseline (326.786 us; speedup 1.0000x reference)
//
#include <hip/hip_runtime.h>
#include <math.h>

// ---------------- problem constants ----------------
namespace {
constexpr int Bn = 4, Sn = 8, Cn = 3, Himg = 256, Wimg = 256;
constexpr int Pn = 68, DS = 4, WIN = 8, STEPS = 10;
constexpr int HWi = Himg * Wimg;            // 65536
constexpr int NIMG = Bn * Sn;               // 32
constexpr int HD = Himg / DS, WD = Wimg / DS; // 64 x 64
constexpr int Kwin = (2 * WIN + 1) * (2 * WIN + 1); // 289
constexpr int CPB = 4;                       // chains per LK block (68 % 4 == 0 -> same b)
constexpr int TPB = 256;                     // 4 waves, 1 per SIMD
}

// ---------------- gray conversion ----------------
__global__ __launch_bounds__(256) void gray_kernel(const float* __restrict__ in,
                                                   float* __restrict__ gray) {
    int idx = blockIdx.x * blockDim.x + threadIdx.x;   // float4 index
    int total = NIMG * HWi / 4;
    if (idx >= total) return;
    int img = idx / (HWi / 4);
    int off = idx % (HWi / 4);
    const float* base = in + (size_t)img * 3 * HWi;
    float4 c0 = ((const float4*)(base))[off];
    float4 c1 = ((const float4*)(base + HWi))[off];
    float4 c2 = ((const float4*)(base + 2 * HWi))[off];
    float4 g;
    g.x = 0.299f * c0.x + 0.587f * c1.x + 0.114f * c2.x;
    g.y = 0.299f * c0.y + 0.587f * c1.y + 0.114f * c2.y;
    g.z = 0.299f * c0.z + 0.587f * c1.z + 0.114f * c2.z;
    g.w = 0.299f * c0.w + 0.587f * c1.w + 0.114f * c2.w;
    ((float4*)(gray + (size_t)img * HWi))[off] = g;
}

// ---------------- detector conv (3x3, stride 4, pad 0 == SAME here) ----------------
__global__ __launch_bounds__(256) void conv_kernel(const float* __restrict__ x,
                                                   const float* __restrict__ Wdet,
                                                   const float* __restrict__ bdet,
                                                   float* __restrict__ hm) {
    __shared__ float wsh[Pn * 27];
    __shared__ float bsh[Pn];
    __shared__ float insh[3][3][Wimg];
    int n = blockIdx.x >> 6;
    int oy = blockIdx.x & 63;
    int tid = threadIdx.x;
    for (int t = tid; t < Pn * 27; t += 256) wsh[t] = Wdet[t];
    if (tid < Pn) bsh[tid] = bdet[tid];
    for (int t = tid; t < 3 * 3 * Wimg; t += 256) {
        int c = t / (3 * Wimg);
        int r = (t / Wimg) % 3;
        int col = t % Wimg;
        insh[c][r][col] = x[(size_t)n * 3 * HWi + (size_t)c * HWi + (oy * 4 + r) * Wimg + col];
    }
    __syncthreads();
    int ox = tid & 63;
    int wid = tid >> 6;
    float in_reg[27];
    #pragma unroll
    for (int c = 0; c < 3; c++)
        #pragma unroll
        for (int ky = 0; ky < 3; ky++)
            #pragma unroll
            for (int kx = 0; kx < 3; kx++)
                in_reg[c * 9 + ky * 3 + kx] = insh[c][ky][ox * 4 + kx];
    #pragma unroll
    for (int i = 0; i < 17; i++) {
        int p = wid + i * 4;
        const float* w = &wsh[p * 27];
        float acc = bsh[p];
        #pragma unroll
        for (int j = 0; j < 27; j++) acc += w[j] * in_reg[j];
        hm[(size_t)n * Pn * 4096 + (size_t)p * 4096 + oy * 64 + ox] = acc;
    }
}

// ---------------- softmax / soft-argmax / scores ----------------
__global__ __launch_bounds__(256) void smax_kernel(const float* __restrict__ hm,
                                                   float* __restrict__ locs,
                                                   float* __restrict__ scos) {
    int row = blockIdx.x;   // n*Pn + p
    const float4* r = (const float4*)(hm + (size_t)row * 4096);
    int tid = threadIdx.x;
    float v[16];
    #pragma unroll
    for (int j = 0; j < 4; j++) {
        float4 q = r[tid + 256 * j];
        v[4 * j + 0] = q.x; v[4 * j + 1] = q.y; v[4 * j + 2] = q.z; v[4 * j + 3] = q.w;
    }
    float m = v[0];
    #pragma unroll
    for (int i = 1; i < 16; i++) m = fmaxf(m, v[i]);
    __shared__ float redm[4];
    #pragma unroll
    for (int o = 32; o; o >>= 1) m = fmaxf(m, __shfl_xor(m, o, 64));
    int wid = tid >> 6, lane = tid & 63;
    if (lane == 0) redm[wid] = m;
    __syncthreads();
    m = fmaxf(fmaxf(redm[0], redm[1]), fmaxf(redm[2], redm[3]));
    float s = 0.f, sx = 0.f, sy = 0.f;
    #pragma unroll
    for (int j = 0; j < 4; j++) {
        #pragma unroll
        for (int q = 0; q < 4; q++) {
            int e = (tid + 256 * j) * 4 + q;
            float ev = expf(v[4 * j + q] - m);
            s += ev;
            sx += ev * (float)(e & 63);
            sy += ev * (float)(e >> 6);
        }
    }
    #pragma unroll
    for (int o = 32; o; o >>= 1) {
        s  += __shfl_xor(s, o, 64);
        sx += __shfl_xor(sx, o, 64);
        sy += __shfl_xor(sy, o, 64);
    }
    __shared__ float reds[3][4];
    if (lane == 0) { reds[0][wid] = s; reds[1][wid] = sx; reds[2][wid] = sy; }
    __syncthreads();
    if (tid == 0) {
        float S_ = reds[0][0] + reds[0][1] + reds[0][2] + reds[0][3];
        float SX = reds[1][0] + reds[1][1] + reds[1][2] + reds[1][3];
        float SY = reds[2][0] + reds[2][1] + reds[2][2] + reds[2][3];
        locs[(size_t)row * 2 + 0] = SX / S_ * 4.0f;
        locs[(size_t)row * 2 + 1] = SY / S_ * 4.0f;
        scos[row] = m;
    }
}

// ---------------- DPP wave64 sum reduction (VALU-only) ----------------
template <int CTRL>
__device__ inline float dpp_add(float v) {
    int t = __builtin_amdgcn_update_dpp(0, __builtin_bit_cast(int, v), CTRL, 0xF, 0xF, true);
    return v + __builtin_bit_cast(float, t);
}

__device__ inline float wredw(float v) {
    v = dpp_add<0x111>(v);   // row_shr:1
    v = dpp_add<0x112>(v);   // row_shr:2
    v = dpp_add<0x114>(v);   // row_shr:4
    v = dpp_add<0x118>(v);   // row_shr:8
    v = dpp_add<0x142>(v);   // row_bcast:15
    v = dpp_add<0x143>(v);   // row_bcast:31
    int s = __builtin_amdgcn_readlane(__builtin_bit_cast(int, v), 63);
    return __builtin_bit_cast(float, s);
}

// ---------------- LK sampling helpers ----------------
template <bool FLY>
__device__ inline float px_at(const float* __restrict__ im, int y, int x) {
    int i = y * Wimg + x;
    if constexpr (FLY)
        return 0.299f * im[i] + 0.587f * im[i + HWi] + 0.114f * im[i + 2 * HWi];
    else
        return im[i];
}

template <bool FLY>
__device__ inline float bilin(const float* __restrict__ im, float x, float y) {
    const float XM = (float)(Wimg - 1.001);
    const float YM = (float)(Himg - 1.001);
    x = fminf(fmaxf(x, 0.0f), XM);
    y = fminf(fmaxf(y, 0.0f), YM);
    float x0f = floorf(x), y0f = floorf(y);
    float wx = x - x0f, wy = y - y0f;
    int x0 = (int)x0f, y0 = (int)y0f;
    int x1 = min(x0 + 1, Wimg - 1), y1 = min(y0 + 1, Himg - 1);
    float v00 = px_at<FLY>(im, y0, x0);
    float v01 = px_at<FLY>(im, y0, x1);
    float v10 = px_at<FLY>(im, y1, x0);
    float v11 = px_at<FLY>(im, y1, x1);
    return (1.0f - wy) * ((1.0f - wx) * v00 + wx * v01) + wy * ((1.0f - wx) * v10 + wx * v11);
}

template <bool FLY>
__device__ inline void sample_tpl(const float* __restrict__ im, float x, float y,
                                  float& I0, float& Ix, float& Iy) {
    const float XM = (float)(Wimg - 1.001);
    const float YM = (float)(Himg - 1.001);
    x = fminf(fmaxf(x, 0.0f), XM);
    y = fminf(fmaxf(y, 0.0f), YM);
    float x0f = floorf(x), y0f = floorf(y);
    float wx = x - x0f, wy = y - y0f;
    int x0 = (int)x0f, y0 = (int)y0f;
    int x1 = min(x0 + 1, Wimg - 1), y1 = min(y0 + 1, Himg - 1);
    int xm = max(x0 - 1, 0), xp = min(x1 + 1, Wimg - 1);
    int ym = max(y0 - 1, 0), yp = min(y1 + 1, Himg - 1);
    float a_m0 = px_at<FLY>(im, ym, x0), a_m1 = px_at<FLY>(im, ym, x1);
    float a_0m = px_at<FLY>(im, y0, xm), a_00 = px_at<FLY>(im, y0, x0);
    float a_01 = px_at<FLY>(im, y0, x1), a_0p = px_at<FLY>(im, y0, xp);
    float a_1m = px_at<FLY>(im, y1, xm), a_10 = px_at<FLY>(im, y1, x0);
    float a_11 = px_at<FLY>(im, y1, x1), a_1p = px_at<FLY>(im, y1, xp);
    float a_p0 = px_at<FLY>(im, yp, x0), a_p1 = px_at<FLY>(im, yp, x1);
    float u = 1.0f - wx, t = 1.0f - wy;
    I0 = t * (u * a_00 + wx * a_01) + wy * (u * a_10 + wx * a_11);
    float gx00 = 0.5f * (a_01 - a_0m);
    float gx01 = 0.5f * (a_0p - a_00);
    float gx10 = 0.5f * (a_11 - a_1m);
    float gx11 = 0.5f * (a_1p - a_10);
    Ix = t * (u * gx00 + wx * gx01) + wy * (u * gx10 + wx * gx11);
    float gy00 = 0.5f * (a_10 - a_m0);
    float gy01 = 0.5f * (a_11 - a_m1);
    float gy10 = 0.5f * (a_p0 - a_00);
    float gy11 = 0.5f * (a_p1 - a_01);
    Iy = t * (u * gy00 + wx * gy01) + wy * (u * gy10 + wx * gy11);
}

// ---------------- 4-chain LK track step (256 threads = 4 waves, 1/SIMD) ----------------
// All threads hold identical px[c],py[c] on entry/exit. Partials: [val][wave] -> float4 read.
template <bool FLY>
__device__ void lk_track4(const float* __restrict__ oldI, const float* __restrict__ newI,
                          float* px, float* py,
                          float dx0, float dy0, float dx1, float dy1, bool act1,
                          int lane, int wid,
                          float (*partG)[CPB][3][4], float (*partB)[CPB][2][4], int& evt) {
    float I00[CPB], Ix0[CPB], Iy0[CPB];
    float I01[CPB], Ix1[CPB], Iy1[CPB];
    float A[CPB], Bv[CPB], D[CPB];
    int ebG = evt & 1; evt++;
    #pragma unroll
    for (int c = 0; c < CPB; c++) {
        float a = 0.f, b = 0.f, g = 0.f;
        sample_tpl<FLY>(oldI, px[c] + dx0, py[c] + dy0, a, b, g);
        I00[c] = a; Ix0[c] = b; Iy0[c] = g;
        float a2 = 0.f, b2 = 0.f, g2 = 0.f;
        if (act1) sample_tpl<FLY>(oldI, px[c] + dx1, py[c] + dy1, a2, b2, g2);
        I01[c] = a2; Ix1[c] = b2; Iy1[c] = g2;
        float gxx = wredw(b * b + b2 * b2);
        float gxy = wredw(b * g + b2 * g2);
        float gyy = wredw(g * g + g2 * g2);
        if (lane == 0) {
            partG[ebG][c][0][wid] = gxx;
            partG[ebG][c][1][wid] = gxy;
            partG[ebG][c][2][wid] = gyy;
        }
    }
    __syncthreads();
    #pragma unroll
    for (int c = 0; c < CPB; c++) {
        float4 g0 = *(const float4*)partG[ebG][c][0];
        float4 g1 = *(const float4*)partG[ebG][c][1];
        float4 g2 = *(const float4*)partG[ebG][c][2];
        float gxx = g0.x + g0.y + g0.z + g0.w;
        float gxy = g1.x + g1.y + g1.z + g1.w;
        float gyy = g2.x + g2.y + g2.z + g2.w;
        float det = gxx * gyy - gxy * gxy + 1e-6f;
        A[c] = gyy / det; Bv[c] = -gxy / det; D[c] = gxx / det;
    }
    float vx[CPB], vy[CPB];
    #pragma unroll
    for (int c = 0; c < CPB; c++) { vx[c] = 0.f; vy[c] = 0.f; }
    for (int it = 0; it < STEPS; ++it) {
        int eb = evt & 1; evt++;
        #pragma unroll
        for (int c = 0; c < CPB; c++) {
            float I1 = bilin<FLY>(newI, px[c] + dx0 + vx[c], py[c] + dy0 + vy[c]);
            float e0 = I00[c] - I1;
            float bx = e0 * Ix0[c];
            float by = e0 * Iy0[c];
            if (act1) {
                float I1b = bilin<FLY>(newI, px[c] + dx1 + vx[c], py[c] + dy1 + vy[c]);
                float e1 = I01[c] - I1b;
                bx += e1 * Ix1[c];
                by += e1 * Iy1[c];
            }
            bx = wredw(bx); by = wredw(by);
            if (lane == 0) {
                partB[eb][c][0][wid] = bx;
                partB[eb][c][1][wid] = by;
            }
        }
        __syncthreads();
        #pragma unroll
        for (int c = 0; c < CPB; c++) {
            float4 b0 = *(const float4*)partB[eb][c][0];
            float4 b1 = *(const float4*)partB[eb][c][1];
            float bx = b0.x + b0.y + b0.z + b0.w;
            float by = b1.x + b1.y + b1.z + b1.w;
            vx[c] += A[c] * bx + Bv[c] * by;
            vy[c] += Bv[c] * bx + D[c] * by;
        }
    }
    #pragma unroll
    for (int c = 0; c < CPB; c++) { px[c] += vx[c]; py[c] += vy[c]; }
}

template <bool FLY>
__global__ __launch_bounds__(TPB) void lk_kernel(const float* __restrict__ grayOrIn,
                                                 const float* __restrict__ locs,
                                                 float* __restrict__ nextPts,
                                                 float* __restrict__ fbackPts,
                                                 float* __restrict__ backPts) {
    constexpr size_t FS = FLY ? (size_t)3 * HWi : (size_t)HWi;
    constexpr int nb0 = (Bn * Pn) / CPB;   // 68 blocks per type
    __shared__ float partG[2][CPB][3][4];
    __shared__ float partB[2][CPB][2][4];
    int g = blockIdx.x;
    int typ = (g < nb0) ? 0 : 1;
    int cb = (typ == 0 ? g : g - nb0) * CPB;   // chain base within its type
    int b = cb / Pn;                           // 68 % 4 == 0 -> same b for all 4 chains
    int pb = cb % Pn;
    int tid = threadIdx.x;
    int lane = tid & 63, wid = tid >> 6;
    // slot 0: k = tid (0..255); slot 1: k = 256+tid for tid < 33
    float dx0 = (float)(tid % 17 - 8);
    float dy0 = (float)(tid / 17 - 8);
    bool act1 = tid < (Kwin - 256);            // 33 lanes
    int k1 = 256 + tid;
    float dx1 = (float)(k1 % 17 - 8);
    float dy1 = (float)(k1 / 17 - 8);
    const float* G = grayOrIn + (size_t)b * Sn * FS;
    int evt = 0;
    auto LIDX = [&](int s, int c) { return (((size_t)b * Sn + s) * Pn + (pb + c)) * 2; };
    float px[CPB], py[CPB];
    if (typ == 0) {
        #pragma unroll
        for (int c = 0; c < CPB; c++) { px[c] = locs[LIDX(0, c)]; py[c] = locs[LIDX(0, c) + 1]; }
        if (tid == 0)
            #pragma unroll
            for (int c = 0; c < CPB; c++) { nextPts[LIDX(0, c)] = px[c]; nextPts[LIDX(0, c) + 1] = py[c]; }
        for (int s = 0; s < 7; s++) {
            lk_track4<FLY>(G + s * FS, G + (s + 1) * FS, px, py, dx0, dy0, dx1, dy1, act1,
                           lane, wid, partG, partB, evt);
            if (tid == 0)
                #pragma unroll
                for (int c = 0; c < CPB; c++) { nextPts[LIDX(s + 1, c)] = px[c]; nextPts[LIDX(s + 1, c) + 1] = py[c]; }
        }
        if (tid == 0)
            #pragma unroll
            for (int c = 0; c < CPB; c++) { fbackPts[LIDX(7, c)] = px[c]; fbackPts[LIDX(7, c) + 1] = py[c]; }
        for (int i = 0; i < 7; i++) {
            lk_track4<FLY>(G + (7 - i) * FS, G + (6 - i) * FS, px, py, dx0, dy0, dx1, dy1, act1,
                           lane, wid, partG, partB, evt);
            if (tid == 0)
                #pragma unroll
                for (int c = 0; c < CPB; c++) { fbackPts[LIDX(6 - i, c)] = px[c]; fbackPts[LIDX(6 - i, c) + 1] = py[c]; }
        }
    } else {
        #pragma unroll
        for (int c = 0; c < CPB; c++) { px[c] = locs[LIDX(7, c)]; py[c] = locs[LIDX(7, c) + 1]; }
        if (tid == 0)
            #pragma unroll
            for (int c = 0; c < CPB; c++) { backPts[LIDX(7, c)] = px[c]; backPts[LIDX(7, c) + 1] = py[c]; }
        for (int i = 0; i < 7; i++) {
            lk_track4<FLY>(G + (7 - i) * FS, G + (6 - i) * FS, px, py, dx0, dy0, dx1, dy1, act1,
                           lane, wid, partG, partB, evt);
            if (tid == 0)
                #pragma unroll
                for (int c = 0; c < CPB; c++) { backPts[LIDX(6 - i, c)] = px[c]; backPts[LIDX(6 - i, c) + 1] = py[c]; }
        }
    }
}

// ---------------- launch ----------------
extern "C" void kernel_launch(void* const* d_in, const int* in_sizes, int n_in,
                              void* d_out, int out_size, void* d_ws, size_t ws_size,
                              hipStream_t stream) {
    const float* inputs = (const float*)d_in[0];
    const float* Wdet = (const float*)d_in[1];
    const float* bdet = (const float*)d_in[2];
    float* out = (float*)d_out;

    const size_t N_hm = (size_t)Bn * Sn * Pn * HD * WD;   // 8,912,896
    const size_t N_pts = (size_t)Bn * Sn * Pn * 2;        // 4352
    float* hm = out;
    float* locs = out + N_hm;
    float* scos = locs + N_pts;
    float* nextPts = scos + (size_t)Bn * Sn * Pn;
    float* fbackPts = nextPts + N_pts;
    float* backPts = fbackPts + N_pts;

    conv_kernel<<<NIMG * 64, 256, 0, stream>>>(inputs, Wdet, bdet, hm);
    smax_kernel<<<NIMG * Pn, 256, 0, stream>>>(hm, locs, scos);

    const int nblk = 2 * ((Bn * Pn) / CPB);  // 68 typ0 + 68 typ1 = 136
    const size_t gray_bytes = (size_t)NIMG * HWi * sizeof(float);  // 8.4 MB
    if (ws_size >= gray_bytes) {
        float* gray = (float*)d_ws;
        gray_kernel<<<(NIMG * HWi / 4 + 255) / 256, 256, 0, stream>>>(inputs, gray);
        lk_kernel<false><<<nblk, TPB, 0, stream>>>(gray, locs, nextPts, fbackPts, backPts);
    } else {
        lk_kernel<true><<<nblk, TPB, 0, stream>>>(inputs, locs, nextPts, fbackPts, backPts);
    }
}

// Round 6
// 137.284 us; speedup vs baseline: 2.3804x; 2.3804x over previous
//
#include <hip/hip_runtime.h>
#include <math.h>

// ---------------- problem constants ----------------
namespace {
constexpr int Bn = 4, Sn = 8, Cn = 3, Himg = 256, Wimg = 256;
constexpr int Pn = 68, DS = 4, WIN = 8, STEPS = 10;
constexpr int HWi = Himg * Wimg;            // 65536
constexpr int NIMG = Bn * Sn;               // 32
constexpr int HD = Himg / DS, WD = Wimg / DS; // 64 x 64
constexpr int Kwin = (2 * WIN + 1) * (2 * WIN + 1); // 289
}

// ---------------- gray conversion ----------------
__global__ __launch_bounds__(256) void gray_kernel(const float* __restrict__ in,
                                                   float* __restrict__ gray) {
    int idx = blockIdx.x * blockDim.x + threadIdx.x;   // float4 index
    int total = NIMG * HWi / 4;
    if (idx >= total) return;
    int img = idx / (HWi / 4);
    int off = idx % (HWi / 4);
    const float* base = in + (size_t)img * 3 * HWi;
    float4 c0 = ((const float4*)(base))[off];
    float4 c1 = ((const float4*)(base + HWi))[off];
    float4 c2 = ((const float4*)(base + 2 * HWi))[off];
    float4 g;
    g.x = 0.299f * c0.x + 0.587f * c1.x + 0.114f * c2.x;
    g.y = 0.299f * c0.y + 0.587f * c1.y + 0.114f * c2.y;
    g.z = 0.299f * c0.z + 0.587f * c1.z + 0.114f * c2.z;
    g.w = 0.299f * c0.w + 0.587f * c1.w + 0.114f * c2.w;
    ((float4*)(gray + (size_t)img * HWi))[off] = g;
}

// ---------------- detector conv (3x3, stride 4, pad 0 == SAME here) ----------------
__global__ __launch_bounds__(256) void conv_kernel(const float* __restrict__ x,
                                                   const float* __restrict__ Wdet,
                                                   const float* __restrict__ bdet,
                                                   float* __restrict__ hm) {
    __shared__ float wsh[Pn * 27];
    __shared__ float bsh[Pn];
    __shared__ float insh[3][3][Wimg];
    int n = blockIdx.x >> 6;
    int oy = blockIdx.x & 63;
    int tid = threadIdx.x;
    for (int t = tid; t < Pn * 27; t += 256) wsh[t] = Wdet[t];
    if (tid < Pn) bsh[tid] = bdet[tid];
    for (int t = tid; t < 3 * 3 * Wimg; t += 256) {
        int c = t / (3 * Wimg);
        int r = (t / Wimg) % 3;
        int col = t % Wimg;
        insh[c][r][col] = x[(size_t)n * 3 * HWi + (size_t)c * HWi + (oy * 4 + r) * Wimg + col];
    }
    __syncthreads();
    int ox = tid & 63;
    int wid = tid >> 6;
    float in_reg[27];
    #pragma unroll
    for (int c = 0; c < 3; c++)
        #pragma unroll
        for (int ky = 0; ky < 3; ky++)
            #pragma unroll
            for (int kx = 0; kx < 3; kx++)
                in_reg[c * 9 + ky * 3 + kx] = insh[c][ky][ox * 4 + kx];
    #pragma unroll
    for (int i = 0; i < 17; i++) {
        int p = wid + i * 4;
        const float* w = &wsh[p * 27];
        float acc = bsh[p];
        #pragma unroll
        for (int j = 0; j < 27; j++) acc += w[j] * in_reg[j];
        hm[(size_t)n * Pn * 4096 + (size_t)p * 4096 + oy * 64 + ox] = acc;
    }
}

// ---------------- softmax / soft-argmax / scores ----------------
__global__ __launch_bounds__(256) void smax_kernel(const float* __restrict__ hm,
                                                   float* __restrict__ locs,
                                                   float* __restrict__ scos) {
    int row = blockIdx.x;   // n*Pn + p
    const float4* r = (const float4*)(hm + (size_t)row * 4096);
    int tid = threadIdx.x;
    float v[16];
    #pragma unroll
    for (int j = 0; j < 4; j++) {
        float4 q = r[tid + 256 * j];
        v[4 * j + 0] = q.x; v[4 * j + 1] = q.y; v[4 * j + 2] = q.z; v[4 * j + 3] = q.w;
    }
    float m = v[0];
    #pragma unroll
    for (int i = 1; i < 16; i++) m = fmaxf(m, v[i]);
    __shared__ float redm[4];
    #pragma unroll
    for (int o = 32; o; o >>= 1) m = fmaxf(m, __shfl_xor(m, o, 64));
    int wid = tid >> 6, lane = tid & 63;
    if (lane == 0) redm[wid] = m;
    __syncthreads();
    m = fmaxf(fmaxf(redm[0], redm[1]), fmaxf(redm[2], redm[3]));
    float s = 0.f, sx = 0.f, sy = 0.f;
    #pragma unroll
    for (int j = 0; j < 4; j++) {
        #pragma unroll
        for (int q = 0; q < 4; q++) {
            int e = (tid + 256 * j) * 4 + q;
            float ev = expf(v[4 * j + q] - m);
            s += ev;
            sx += ev * (float)(e & 63);
            sy += ev * (float)(e >> 6);
        }
    }
    #pragma unroll
    for (int o = 32; o; o >>= 1) {
        s  += __shfl_xor(s, o, 64);
        sx += __shfl_xor(sx, o, 64);
        sy += __shfl_xor(sy, o, 64);
    }
    __shared__ float reds[3][4];
    if (lane == 0) { reds[0][wid] = s; reds[1][wid] = sx; reds[2][wid] = sy; }
    __syncthreads();
    if (tid == 0) {
        float S_ = reds[0][0] + reds[0][1] + reds[0][2] + reds[0][3];
        float SX = reds[1][0] + reds[1][1] + reds[1][2] + reds[1][3];
        float SY = reds[2][0] + reds[2][1] + reds[2][2] + reds[2][3];
        locs[(size_t)row * 2 + 0] = SX / S_ * 4.0f;
        locs[(size_t)row * 2 + 1] = SY / S_ * 4.0f;
        scos[row] = m;
    }
}

// ---------------- DPP wave64 sum reduction (VALU-only) ----------------
template <int CTRL>
__device__ inline float dpp_add(float v) {
    int t = __builtin_amdgcn_update_dpp(0, __builtin_bit_cast(int, v), CTRL, 0xF, 0xF, true);
    return v + __builtin_bit_cast(float, t);
}

__device__ inline float wredw(float v) {
    v = dpp_add<0x111>(v);   // row_shr:1
    v = dpp_add<0x112>(v);   // row_shr:2
    v = dpp_add<0x114>(v);   // row_shr:4
    v = dpp_add<0x118>(v);   // row_shr:8
    v = dpp_add<0x142>(v);   // row_bcast:15
    v = dpp_add<0x143>(v);   // row_bcast:31
    int s = __builtin_amdgcn_readlane(__builtin_bit_cast(int, v), 63);
    return __builtin_bit_cast(float, s);
}

// ---------------- LK: 1 wave/chain, branch-free 5-slot sampling ----------------
template <bool FLY>
__device__ inline float px_at(const float* __restrict__ im, int idx) {
    if constexpr (FLY)
        return 0.299f * im[idx] + 0.587f * im[idx + HWi] + 0.114f * im[idx + 2 * HWi];
    else
        return im[idx];
}

// One LK track step for one chain on ONE wave. px,py identical across lanes.
// Slots j=0..3 fully active; slot 4 active lanes<33, gradients masked by s4w.
template <bool FLY>
__device__ void lk_track(const float* __restrict__ oldI, const float* __restrict__ newI,
                         float& px, float& py, const float* dxs, const float* dys,
                         float s4w) {
    const float XM = (float)(Wimg - 1.001);
    const float YM = (float)(Himg - 1.001);
    float I0[5], Ix[5], Iy[5];
    // ---- template phase: 5 slots x 12 gathered pixels, straight-line ----
    {
        float wx[5], wy[5];
        int a_ym[5], a_y0[5], a_y1[5], a_yp[5];   // row base indices
        int xm[5], x0[5], x1[5], xp[5];
        #pragma unroll
        for (int j = 0; j < 5; j++) {
            float x = fminf(fmaxf(px + dxs[j], 0.0f), XM);
            float y = fminf(fmaxf(py + dys[j], 0.0f), YM);
            float x0f = floorf(x), y0f = floorf(y);
            wx[j] = x - x0f; wy[j] = y - y0f;
            int xi = (int)x0f, yi = (int)y0f;
            x0[j] = xi;
            x1[j] = min(xi + 1, Wimg - 1);
            xm[j] = max(xi - 1, 0);
            xp[j] = min(xi + 2, Wimg - 1);
            a_y0[j] = yi * Wimg;
            a_y1[j] = min(yi + 1, Himg - 1) * Wimg;
            a_ym[j] = max(yi - 1, 0) * Wimg;
            a_yp[j] = min(yi + 2, Himg - 1) * Wimg;
        }
        float m0[5], m1[5], c0m[5], c00[5], c01[5], c0p[5], c1m[5], c10[5], c11[5], c1p[5], p0[5], p1[5];
        #pragma unroll
        for (int j = 0; j < 5; j++) {
            m0[j] = px_at<FLY>(oldI, a_ym[j] + x0[j]);
            m1[j] = px_at<FLY>(oldI, a_ym[j] + x1[j]);
            c0m[j] = px_at<FLY>(oldI, a_y0[j] + xm[j]);
            c00[j] = px_at<FLY>(oldI, a_y0[j] + x0[j]);
            c01[j] = px_at<FLY>(oldI, a_y0[j] + x1[j]);
            c0p[j] = px_at<FLY>(oldI, a_y0[j] + xp[j]);
            c1m[j] = px_at<FLY>(oldI, a_y1[j] + xm[j]);
            c10[j] = px_at<FLY>(oldI, a_y1[j] + x0[j]);
            c11[j] = px_at<FLY>(oldI, a_y1[j] + x1[j]);
            c1p[j] = px_at<FLY>(oldI, a_y1[j] + xp[j]);
            p0[j] = px_at<FLY>(oldI, a_yp[j] + x0[j]);
            p1[j] = px_at<FLY>(oldI, a_yp[j] + x1[j]);
        }
        #pragma unroll
        for (int j = 0; j < 5; j++) {
            float u = 1.0f - wx[j], t = 1.0f - wy[j];
            I0[j] = t * (u * c00[j] + wx[j] * c01[j]) + wy[j] * (u * c10[j] + wx[j] * c11[j]);
            float gx00 = 0.5f * (c01[j] - c0m[j]);
            float gx01 = 0.5f * (c0p[j] - c00[j]);
            float gx10 = 0.5f * (c11[j] - c1m[j]);
            float gx11 = 0.5f * (c1p[j] - c10[j]);
            Ix[j] = t * (u * gx00 + wx[j] * gx01) + wy[j] * (u * gx10 + wx[j] * gx11);
            float gy00 = 0.5f * (c10[j] - m0[j]);
            float gy01 = 0.5f * (c11[j] - m1[j]);
            float gy10 = 0.5f * (p0[j] - c00[j]);
            float gy11 = 0.5f * (p1[j] - c01[j]);
            Iy[j] = t * (u * gy00 + wx[j] * gy01) + wy[j] * (u * gy10 + wx[j] * gy11);
        }
        Ix[4] *= s4w;   // mask slot-4 contributions for lanes >= 33
        Iy[4] *= s4w;
    }
    float gxx = 0.f, gxy = 0.f, gyy = 0.f;
    #pragma unroll
    for (int j = 0; j < 5; j++) { gxx += Ix[j] * Ix[j]; gxy += Ix[j] * Iy[j]; gyy += Iy[j] * Iy[j]; }
    gxx = wredw(gxx); gxy = wredw(gxy); gyy = wredw(gyy);
    float det = gxx * gyy - gxy * gxy + 1e-6f;
    float A = gyy / det, Bv = -gxy / det, D = gxx / det;  // Ginv
    float vx = 0.f, vy = 0.f;
    // ---- Gauss-Newton loop: branch-free, 20 batched loads per iter ----
    for (int it = 0; it < STEPS; ++it) {
        float fx[5], fy[5];
        int ad[5], dx1[5], dy1[5];
        #pragma unroll
        for (int j = 0; j < 5; j++) {
            float x = fminf(fmaxf(px + dxs[j] + vx, 0.0f), XM);
            float y = fminf(fmaxf(py + dys[j] + vy, 0.0f), YM);
            float x0f = floorf(x), y0f = floorf(y);
            fx[j] = x - x0f; fy[j] = y - y0f;
            int xi = (int)x0f, yi = (int)y0f;
            ad[j] = yi * Wimg + xi;
            dx1[j] = min(xi + 1, Wimg - 1) - xi;                 // 0 or 1
            dy1[j] = (min(yi + 1, Himg - 1) - yi) * Wimg;        // 0 or 256
        }
        float v00[5], v01[5], v10[5], v11[5];
        #pragma unroll
        for (int j = 0; j < 5; j++) {
            v00[j] = px_at<FLY>(newI, ad[j]);
            v01[j] = px_at<FLY>(newI, ad[j] + dx1[j]);
            v10[j] = px_at<FLY>(newI, ad[j] + dy1[j]);
            v11[j] = px_at<FLY>(newI, ad[j] + dy1[j] + dx1[j]);
        }
        float bx = 0.f, by = 0.f;
        #pragma unroll
        for (int j = 0; j < 5; j++) {
            float u = 1.0f - fx[j], t = 1.0f - fy[j];
            float I1 = t * (u * v00[j] + fx[j] * v01[j]) + fy[j] * (u * v10[j] + fx[j] * v11[j]);
            float err = I0[j] - I1;
            bx += err * Ix[j];
            by += err * Iy[j];
        }
        bx = wredw(bx); by = wredw(by);
        vx += A * bx + Bv * by;
        vy += Bv * bx + D * by;
    }
    px += vx; py += vy;
}

template <bool FLY>
__global__ __launch_bounds__(64) void lk_kernel(const float* __restrict__ grayOrIn,
                                                const float* __restrict__ locs,
                                                float* __restrict__ nextPts,
                                                float* __restrict__ fbackPts,
                                                float* __restrict__ backPts) {
    constexpr size_t FS = FLY ? (size_t)3 * HWi : (size_t)HWi;  // frame stride
    int g = blockIdx.x;
    int typ = g / (Bn * Pn);
    int r = g % (Bn * Pn);
    int b = r / Pn;
    int p = r % Pn;
    int lane = threadIdx.x;
    const float* G = grayOrIn + (size_t)b * Sn * FS;
    float dxs[5], dys[5];
    #pragma unroll
    for (int j = 0; j < 4; j++) {
        int k = lane + 64 * j;
        dxs[j] = (float)(k % 17 - 8);
        dys[j] = (float)(k / 17 - 8);
    }
    {
        int k4 = (lane < Kwin - 256) ? 256 + lane : 256;   // clamped dummy for lanes >= 33
        dxs[4] = (float)(k4 % 17 - 8);
        dys[4] = (float)(k4 / 17 - 8);
    }
    float s4w = (lane < Kwin - 256) ? 1.0f : 0.0f;
    auto LIDX = [&](int s) { return (((size_t)b * Sn + s) * Pn + p) * 2; };
    if (typ == 0) {
        float px = locs[LIDX(0)], py = locs[LIDX(0) + 1];
        if (lane == 0) { nextPts[LIDX(0)] = px; nextPts[LIDX(0) + 1] = py; }
        for (int s = 0; s < 7; s++) {
            lk_track<FLY>(G + s * FS, G + (s + 1) * FS, px, py, dxs, dys, s4w);
            if (lane == 0) { nextPts[LIDX(s + 1)] = px; nextPts[LIDX(s + 1) + 1] = py; }
        }
        if (lane == 0) { fbackPts[LIDX(7)] = px; fbackPts[LIDX(7) + 1] = py; }
        for (int i = 0; i < 7; i++) {
            lk_track<FLY>(G + (7 - i) * FS, G + (6 - i) * FS, px, py, dxs, dys, s4w);
            if (lane == 0) { fbackPts[LIDX(6 - i)] = px; fbackPts[LIDX(6 - i) + 1] = py; }
        }
    } else {
        float px = locs[LIDX(7)], py = locs[LIDX(7) + 1];
        if (lane == 0) { backPts[LIDX(7)] = px; backPts[LIDX(7) + 1] = py; }
        for (int i = 0; i < 7; i++) {
            lk_track<FLY>(G + (7 - i) * FS, G + (6 - i) * FS, px, py, dxs, dys, s4w);
            if (lane == 0) { backPts[LIDX(6 - i)] = px; backPts[LIDX(6 - i) + 1] = py; }
        }
    }
}

// ---------------- launch ----------------
extern "C" void kernel_launch(void* const* d_in, const int* in_sizes, int n_in,
                              void* d_out, int out_size, void* d_ws, size_t ws_size,
                              hipStream_t stream) {
    const float* inputs = (const float*)d_in[0];
    const float* Wdet = (const float*)d_in[1];
    const float* bdet = (const float*)d_in[2];
    float* out = (float*)d_out;

    const size_t N_hm = (size_t)Bn * Sn * Pn * HD * WD;   // 8,912,896
    const size_t N_pts = (size_t)Bn * Sn * Pn * 2;        // 4352
    float* hm = out;
    float* locs = out + N_hm;
    float* scos = locs + N_pts;
    float* nextPts = scos + (size_t)Bn * Sn * Pn;
    float* fbackPts = nextPts + N_pts;
    float* backPts = fbackPts + N_pts;

    conv_kernel<<<NIMG * 64, 256, 0, stream>>>(inputs, Wdet, bdet, hm);
    smax_kernel<<<NIMG * Pn, 256, 0, stream>>>(hm, locs, scos);

    const size_t gray_bytes = (size_t)NIMG * HWi * sizeof(float);  // 8.4 MB
    if (ws_size >= gray_bytes) {
        float* gray = (float*)d_ws;
        gray_kernel<<<(NIMG * HWi / 4 + 255) / 256, 256, 0, stream>>>(inputs, gray);
        lk_kernel<false><<<2 * Bn * Pn, 64, 0, stream>>>(gray, locs, nextPts, fbackPts, backPts);
    } else {
        lk_kernel<true><<<2 * Bn * Pn, 64, 0, stream>>>(inputs, locs, nextPts, fbackPts, backPts);
    }
}

// Round 7
// 121.665 us; speedup vs baseline: 2.6859x; 1.1284x over previous
//
#include <hip/hip_runtime.h>
#include <math.h>

// ---------------- problem constants ----------------
namespace {
constexpr int Bn = 4, Sn = 8, Cn = 3, Himg = 256, Wimg = 256;
constexpr int Pn = 68, DS = 4, WIN = 8, STEPS = 10;
constexpr int HWi = Himg * Wimg;            // 65536
constexpr int NIMG = Bn * Sn;               // 32
constexpr int HD = Himg / DS, WD = Wimg / DS; // 64 x 64
constexpr int Kwin = (2 * WIN + 1) * (2 * WIN + 1); // 289
}

// ---------------- gray conversion + 1px-shifted copy ----------------
__global__ __launch_bounds__(256) void gray2_kernel(const float* __restrict__ in,
                                                    float* __restrict__ gray,
                                                    float* __restrict__ sh) {
    int idx = blockIdx.x * blockDim.x + threadIdx.x;   // float4 index
    int total = NIMG * HWi / 4;
    if (idx >= total) return;
    int img = idx / (HWi / 4);
    int off = idx % (HWi / 4);
    const float* base = in + (size_t)img * 3 * HWi;
    float4 c0 = ((const float4*)(base))[off];
    float4 c1 = ((const float4*)(base + HWi))[off];
    float4 c2 = ((const float4*)(base + 2 * HWi))[off];
    float4 g;
    g.x = 0.299f * c0.x + 0.587f * c1.x + 0.114f * c2.x;
    g.y = 0.299f * c0.y + 0.587f * c1.y + 0.114f * c2.y;
    g.z = 0.299f * c0.z + 0.587f * c1.z + 0.114f * c2.z;
    g.w = 0.299f * c0.w + 0.587f * c1.w + 0.114f * c2.w;
    // gray value of next global element (4*idx+4), for the shifted array
    float gn = 0.f;
    int gi = idx * 4 + 4;
    if (gi < NIMG * HWi) {
        int i2 = gi / HWi;
        int o2 = gi % HWi;
        const float* b2 = in + (size_t)i2 * 3 * HWi;
        gn = 0.299f * b2[o2] + 0.587f * b2[o2 + HWi] + 0.114f * b2[o2 + 2 * HWi];
    }
    ((float4*)(gray + (size_t)img * HWi))[off] = g;
    float4 s;
    s.x = g.y; s.y = g.z; s.z = g.w; s.w = gn;
    ((float4*)(sh + (size_t)img * HWi))[off] = s;
}

// ---------------- detector conv (3x3, stride 4, pad 0 == SAME here) ----------------
__global__ __launch_bounds__(256) void conv_kernel(const float* __restrict__ x,
                                                   const float* __restrict__ Wdet,
                                                   const float* __restrict__ bdet,
                                                   float* __restrict__ hm) {
    __shared__ float wsh[Pn * 27];
    __shared__ float bsh[Pn];
    __shared__ float insh[3][3][Wimg];
    int n = blockIdx.x >> 6;
    int oy = blockIdx.x & 63;
    int tid = threadIdx.x;
    for (int t = tid; t < Pn * 27; t += 256) wsh[t] = Wdet[t];
    if (tid < Pn) bsh[tid] = bdet[tid];
    for (int t = tid; t < 3 * 3 * Wimg; t += 256) {
        int c = t / (3 * Wimg);
        int r = (t / Wimg) % 3;
        int col = t % Wimg;
        insh[c][r][col] = x[(size_t)n * 3 * HWi + (size_t)c * HWi + (oy * 4 + r) * Wimg + col];
    }
    __syncthreads();
    int ox = tid & 63;
    int wid = tid >> 6;
    float in_reg[27];
    #pragma unroll
    for (int c = 0; c < 3; c++)
        #pragma unroll
        for (int ky = 0; ky < 3; ky++)
            #pragma unroll
            for (int kx = 0; kx < 3; kx++)
                in_reg[c * 9 + ky * 3 + kx] = insh[c][ky][ox * 4 + kx];
    #pragma unroll
    for (int i = 0; i < 17; i++) {
        int p = wid + i * 4;
        const float* w = &wsh[p * 27];
        float acc = bsh[p];
        #pragma unroll
        for (int j = 0; j < 27; j++) acc += w[j] * in_reg[j];
        hm[(size_t)n * Pn * 4096 + (size_t)p * 4096 + oy * 64 + ox] = acc;
    }
}

// ---------------- softmax / soft-argmax / scores ----------------
__global__ __launch_bounds__(256) void smax_kernel(const float* __restrict__ hm,
                                                   float* __restrict__ locs,
                                                   float* __restrict__ scos) {
    int row = blockIdx.x;   // n*Pn + p
    const float4* r = (const float4*)(hm + (size_t)row * 4096);
    int tid = threadIdx.x;
    float v[16];
    #pragma unroll
    for (int j = 0; j < 4; j++) {
        float4 q = r[tid + 256 * j];
        v[4 * j + 0] = q.x; v[4 * j + 1] = q.y; v[4 * j + 2] = q.z; v[4 * j + 3] = q.w;
    }
    float m = v[0];
    #pragma unroll
    for (int i = 1; i < 16; i++) m = fmaxf(m, v[i]);
    __shared__ float redm[4];
    #pragma unroll
    for (int o = 32; o; o >>= 1) m = fmaxf(m, __shfl_xor(m, o, 64));
    int wid = tid >> 6, lane = tid & 63;
    if (lane == 0) redm[wid] = m;
    __syncthreads();
    m = fmaxf(fmaxf(redm[0], redm[1]), fmaxf(redm[2], redm[3]));
    float s = 0.f, sx = 0.f, sy = 0.f;
    #pragma unroll
    for (int j = 0; j < 4; j++) {
        #pragma unroll
        for (int q = 0; q < 4; q++) {
            int e = (tid + 256 * j) * 4 + q;
            float ev = expf(v[4 * j + q] - m);
            s += ev;
            sx += ev * (float)(e & 63);
            sy += ev * (float)(e >> 6);
        }
    }
    #pragma unroll
    for (int o = 32; o; o >>= 1) {
        s  += __shfl_xor(s, o, 64);
        sx += __shfl_xor(sx, o, 64);
        sy += __shfl_xor(sy, o, 64);
    }
    __shared__ float reds[3][4];
    if (lane == 0) { reds[0][wid] = s; reds[1][wid] = sx; reds[2][wid] = sy; }
    __syncthreads();
    if (tid == 0) {
        float S_ = reds[0][0] + reds[0][1] + reds[0][2] + reds[0][3];
        float SX = reds[1][0] + reds[1][1] + reds[1][2] + reds[1][3];
        float SY = reds[2][0] + reds[2][1] + reds[2][2] + reds[2][3];
        locs[(size_t)row * 2 + 0] = SX / S_ * 4.0f;
        locs[(size_t)row * 2 + 1] = SY / S_ * 4.0f;
        scos[row] = m;
    }
}

// ---------------- DPP wave64 sum reduction (VALU-only) ----------------
template <int CTRL>
__device__ inline float dpp_add(float v) {
    int t = __builtin_amdgcn_update_dpp(0, __builtin_bit_cast(int, v), CTRL, 0xF, 0xF, true);
    return v + __builtin_bit_cast(float, t);
}

__device__ inline float wredw(float v) {
    v = dpp_add<0x111>(v);   // row_shr:1
    v = dpp_add<0x112>(v);   // row_shr:2
    v = dpp_add<0x114>(v);   // row_shr:4
    v = dpp_add<0x118>(v);   // row_shr:8
    v = dpp_add<0x142>(v);   // row_bcast:15
    v = dpp_add<0x143>(v);   // row_bcast:31
    int s = __builtin_amdgcn_readlane(__builtin_bit_cast(int, v), 63);
    return __builtin_bit_cast(float, s);
}

// ---------------- LK pair-load track step (1 wave/chain) ----------------
// oldI/newI: gray frames; oldS/newS: 1px-shifted copies (sh[i] == gray[i+1]).
// Slots j=0..3 fully active; slot 4 active lanes<33, gradients masked by s4w.
__device__ void lk_track_pair(const float* __restrict__ oldI, const float* __restrict__ oldS,
                              const float* __restrict__ newI, const float* __restrict__ newS,
                              float& px, float& py, const float* dxs, const float* dys,
                              float s4w) {
    const float XM = (float)(Wimg - 1.001);
    const float YM = (float)(Himg - 1.001);
    float I0[5], Ix[5], Iy[5], qx[5], qy[5];
    // ---- template phase: 4 pair-loads + 4 scalar loads per slot ----
    {
        float wx[5], wy[5];
        const float* pb[5];
        int xe[5], am[5], a0[5], a1[5], ap[5], xm[5], xp[5];
        #pragma unroll
        for (int j = 0; j < 5; j++) {
            qx[j] = px + dxs[j];
            qy[j] = py + dys[j];
            float x = fminf(fmaxf(qx[j], 0.0f), XM);
            float y = fminf(fmaxf(qy[j], 0.0f), YM);
            float x0f = floorf(x), y0f = floorf(y);
            wx[j] = x - x0f; wy[j] = y - y0f;
            int xi = (int)x0f, yi = (int)y0f;
            xe[j] = xi & ~1;
            pb[j] = (xi & 1) ? oldS : oldI;
            xm[j] = max(xi - 1, 0);
            xp[j] = min(xi + 2, Wimg - 1);
            a0[j] = yi * Wimg;
            a1[j] = a0[j] + Wimg;                 // yi+1 <= 255 always
            am[j] = max(yi - 1, 0) * Wimg;
            ap[j] = min(yi + 2, Himg - 1) * Wimg;
        }
        float2 Pm[5], P0[5], P1[5], Pp[5];
        float c0m[5], c0p[5], c1m[5], c1p[5];
        #pragma unroll
        for (int j = 0; j < 5; j++) {
            Pm[j] = *(const float2*)(pb[j] + am[j] + xe[j]);
            P0[j] = *(const float2*)(pb[j] + a0[j] + xe[j]);
            P1[j] = *(const float2*)(pb[j] + a1[j] + xe[j]);
            Pp[j] = *(const float2*)(pb[j] + ap[j] + xe[j]);
            c0m[j] = oldI[a0[j] + xm[j]];
            c0p[j] = oldI[a0[j] + xp[j]];
            c1m[j] = oldI[a1[j] + xm[j]];
            c1p[j] = oldI[a1[j] + xp[j]];
        }
        #pragma unroll
        for (int j = 0; j < 5; j++) {
            float m0 = Pm[j].x, m1 = Pm[j].y;
            float c00 = P0[j].x, c01 = P0[j].y;
            float c10 = P1[j].x, c11 = P1[j].y;
            float p0 = Pp[j].x, p1 = Pp[j].y;
            float u = 1.0f - wx[j], t = 1.0f - wy[j];
            I0[j] = t * (u * c00 + wx[j] * c01) + wy[j] * (u * c10 + wx[j] * c11);
            float gx00 = 0.5f * (c01 - c0m[j]);
            float gx01 = 0.5f * (c0p[j] - c00);
            float gx10 = 0.5f * (c11 - c1m[j]);
            float gx11 = 0.5f * (c1p[j] - c10);
            Ix[j] = t * (u * gx00 + wx[j] * gx01) + wy[j] * (u * gx10 + wx[j] * gx11);
            float gy00 = 0.5f * (c10 - m0);
            float gy01 = 0.5f * (c11 - m1);
            float gy10 = 0.5f * (p0 - c00);
            float gy11 = 0.5f * (p1 - c01);
            Iy[j] = t * (u * gy00 + wx[j] * gy01) + wy[j] * (u * gy10 + wx[j] * gy11);
        }
        Ix[4] *= s4w;
        Iy[4] *= s4w;
    }
    float gxx = 0.f, gxy = 0.f, gyy = 0.f;
    #pragma unroll
    for (int j = 0; j < 5; j++) { gxx += Ix[j] * Ix[j]; gxy += Ix[j] * Iy[j]; gyy += Iy[j] * Iy[j]; }
    gxx = wredw(gxx); gxy = wredw(gxy); gyy = wredw(gyy);
    float det = gxx * gyy - gxy * gxy + 1e-6f;
    float A = gyy / det, Bv = -gxy / det, D = gxx / det;  // Ginv
    float vx = 0.f, vy = 0.f;
    // ---- Gauss-Newton loop: 10 pair-loads per iter ----
    for (int it = 0; it < STEPS; ++it) {
        float fx[5], fy[5];
        const float* pb[5];
        int aa[5];
        #pragma unroll
        for (int j = 0; j < 5; j++) {
            float x = fminf(fmaxf(qx[j] + vx, 0.0f), XM);
            float y = fminf(fmaxf(qy[j] + vy, 0.0f), YM);
            float x0f = floorf(x), y0f = floorf(y);
            fx[j] = x - x0f; fy[j] = y - y0f;
            int xi = (int)x0f, yi = (int)y0f;
            pb[j] = (xi & 1) ? newS : newI;
            aa[j] = yi * Wimg + (xi & ~1);
        }
        float2 R0[5], R1[5];
        #pragma unroll
        for (int j = 0; j < 5; j++) {
            R0[j] = *(const float2*)(pb[j] + aa[j]);
            R1[j] = *(const float2*)(pb[j] + aa[j] + Wimg);
        }
        float bx = 0.f, by = 0.f;
        #pragma unroll
        for (int j = 0; j < 5; j++) {
            float u = 1.0f - fx[j], t = 1.0f - fy[j];
            float I1 = t * (u * R0[j].x + fx[j] * R0[j].y) + fy[j] * (u * R1[j].x + fx[j] * R1[j].y);
            float err = I0[j] - I1;
            bx += err * Ix[j];
            by += err * Iy[j];
        }
        bx = wredw(bx); by = wredw(by);
        vx += A * bx + Bv * by;
        vy += Bv * bx + D * by;
    }
    px += vx; py += vy;
}

__global__ __launch_bounds__(64) void lk_pair_kernel(const float* __restrict__ gray,
                                                     const float* __restrict__ sh,
                                                     const float* __restrict__ locs,
                                                     float* __restrict__ nextPts,
                                                     float* __restrict__ fbackPts,
                                                     float* __restrict__ backPts) {
    int g = blockIdx.x;
    int typ = g / (Bn * Pn);
    int r = g % (Bn * Pn);
    int b = r / Pn;
    int p = r % Pn;
    int lane = threadIdx.x;
    const float* G = gray + (size_t)b * Sn * HWi;
    const float* S = sh + (size_t)b * Sn * HWi;
    float dxs[5], dys[5];
    #pragma unroll
    for (int j = 0; j < 4; j++) {
        int k = lane + 64 * j;
        dxs[j] = (float)(k % 17 - 8);
        dys[j] = (float)(k / 17 - 8);
    }
    {
        int k4 = (lane < Kwin - 256) ? 256 + lane : 256;
        dxs[4] = (float)(k4 % 17 - 8);
        dys[4] = (float)(k4 / 17 - 8);
    }
    float s4w = (lane < Kwin - 256) ? 1.0f : 0.0f;
    auto LIDX = [&](int s) { return (((size_t)b * Sn + s) * Pn + p) * 2; };
    if (typ == 0) {
        float px = locs[LIDX(0)], py = locs[LIDX(0) + 1];
        if (lane == 0) { nextPts[LIDX(0)] = px; nextPts[LIDX(0) + 1] = py; }
        for (int s = 0; s < 7; s++) {
            lk_track_pair(G + s * HWi, S + s * HWi, G + (s + 1) * HWi, S + (s + 1) * HWi,
                          px, py, dxs, dys, s4w);
            if (lane == 0) { nextPts[LIDX(s + 1)] = px; nextPts[LIDX(s + 1) + 1] = py; }
        }
        if (lane == 0) { fbackPts[LIDX(7)] = px; fbackPts[LIDX(7) + 1] = py; }
        for (int i = 0; i < 7; i++) {
            lk_track_pair(G + (7 - i) * HWi, S + (7 - i) * HWi, G + (6 - i) * HWi, S + (6 - i) * HWi,
                          px, py, dxs, dys, s4w);
            if (lane == 0) { fbackPts[LIDX(6 - i)] = px; fbackPts[LIDX(6 - i) + 1] = py; }
        }
    } else {
        float px = locs[LIDX(7)], py = locs[LIDX(7) + 1];
        if (lane == 0) { backPts[LIDX(7)] = px; backPts[LIDX(7) + 1] = py; }
        for (int i = 0; i < 7; i++) {
            lk_track_pair(G + (7 - i) * HWi, S + (7 - i) * HWi, G + (6 - i) * HWi, S + (6 - i) * HWi,
                          px, py, dxs, dys, s4w);
            if (lane == 0) { backPts[LIDX(6 - i)] = px; backPts[LIDX(6 - i) + 1] = py; }
        }
    }
}

// ---------------- fallback (ws too small): round-6 scalar on-the-fly gray ----------------
__device__ inline float px_fly(const float* __restrict__ im, int idx) {
    return 0.299f * im[idx] + 0.587f * im[idx + HWi] + 0.114f * im[idx + 2 * HWi];
}

__device__ void lk_track_fly(const float* __restrict__ oldI, const float* __restrict__ newI,
                             float& px, float& py, const float* dxs, const float* dys,
                             float s4w) {
    const float XM = (float)(Wimg - 1.001);
    const float YM = (float)(Himg - 1.001);
    float I0[5], Ix[5], Iy[5], qx[5], qy[5];
    {
        float wx[5], wy[5];
        int am[5], a0[5], a1[5], ap[5], xm[5], x0[5], x1[5], xp[5];
        #pragma unroll
        for (int j = 0; j < 5; j++) {
            qx[j] = px + dxs[j]; qy[j] = py + dys[j];
            float x = fminf(fmaxf(qx[j], 0.0f), XM);
            float y = fminf(fmaxf(qy[j], 0.0f), YM);
            float x0f = floorf(x), y0f = floorf(y);
            wx[j] = x - x0f; wy[j] = y - y0f;
            int xi = (int)x0f, yi = (int)y0f;
            x0[j] = xi; x1[j] = min(xi + 1, Wimg - 1);
            xm[j] = max(xi - 1, 0); xp[j] = min(xi + 2, Wimg - 1);
            a0[j] = yi * Wimg;
            a1[j] = min(yi + 1, Himg - 1) * Wimg;
            am[j] = max(yi - 1, 0) * Wimg;
            ap[j] = min(yi + 2, Himg - 1) * Wimg;
        }
        #pragma unroll
        for (int j = 0; j < 5; j++) {
            float m0 = px_fly(oldI, am[j] + x0[j]), m1 = px_fly(oldI, am[j] + x1[j]);
            float c0m = px_fly(oldI, a0[j] + xm[j]), c00 = px_fly(oldI, a0[j] + x0[j]);
            float c01 = px_fly(oldI, a0[j] + x1[j]), c0p = px_fly(oldI, a0[j] + xp[j]);
            float c1m = px_fly(oldI, a1[j] + xm[j]), c10 = px_fly(oldI, a1[j] + x0[j]);
            float c11 = px_fly(oldI, a1[j] + x1[j]), c1p = px_fly(oldI, a1[j] + xp[j]);
            float p0 = px_fly(oldI, ap[j] + x0[j]), p1 = px_fly(oldI, ap[j] + x1[j]);
            float u = 1.0f - wx[j], t = 1.0f - wy[j];
            I0[j] = t * (u * c00 + wx[j] * c01) + wy[j] * (u * c10 + wx[j] * c11);
            Ix[j] = t * (u * 0.5f * (c01 - c0m) + wx[j] * 0.5f * (c0p - c00))
                  + wy[j] * (u * 0.5f * (c11 - c1m) + wx[j] * 0.5f * (c1p - c10));
            Iy[j] = t * (u * 0.5f * (c10 - m0) + wx[j] * 0.5f * (c11 - m1))
                  + wy[j] * (u * 0.5f * (p0 - c00) + wx[j] * 0.5f * (p1 - c01));
        }
        Ix[4] *= s4w; Iy[4] *= s4w;
    }
    float gxx = 0.f, gxy = 0.f, gyy = 0.f;
    #pragma unroll
    for (int j = 0; j < 5; j++) { gxx += Ix[j] * Ix[j]; gxy += Ix[j] * Iy[j]; gyy += Iy[j] * Iy[j]; }
    gxx = wredw(gxx); gxy = wredw(gxy); gyy = wredw(gyy);
    float det = gxx * gyy - gxy * gxy + 1e-6f;
    float A = gyy / det, Bv = -gxy / det, D = gxx / det;
    float vx = 0.f, vy = 0.f;
    for (int it = 0; it < STEPS; ++it) {
        float bx = 0.f, by = 0.f;
        #pragma unroll
        for (int j = 0; j < 5; j++) {
            float x = fminf(fmaxf(qx[j] + vx, 0.0f), XM);
            float y = fminf(fmaxf(qy[j] + vy, 0.0f), YM);
            float x0f = floorf(x), y0f = floorf(y);
            float fxx = x - x0f, fyy = y - y0f;
            int xi = (int)x0f, yi = (int)y0f;
            int ad = yi * Wimg + xi;
            float v00 = px_fly(newI, ad), v01 = px_fly(newI, ad + 1);
            float v10 = px_fly(newI, ad + Wimg), v11 = px_fly(newI, ad + Wimg + 1);
            float u = 1.0f - fxx, t = 1.0f - fyy;
            float I1 = t * (u * v00 + fxx * v01) + fyy * (u * v10 + fxx * v11);
            float err = I0[j] - I1;
            bx += err * Ix[j];
            by += err * Iy[j];
        }
        bx = wredw(bx); by = wredw(by);
        vx += A * bx + Bv * by;
        vy += Bv * bx + D * by;
    }
    px += vx; py += vy;
}

__global__ __launch_bounds__(64) void lk_fly_kernel(const float* __restrict__ in,
                                                    const float* __restrict__ locs,
                                                    float* __restrict__ nextPts,
                                                    float* __restrict__ fbackPts,
                                                    float* __restrict__ backPts) {
    constexpr size_t FS = (size_t)3 * HWi;
    int g = blockIdx.x;
    int typ = g / (Bn * Pn);
    int r = g % (Bn * Pn);
    int b = r / Pn;
    int p = r % Pn;
    int lane = threadIdx.x;
    const float* G = in + (size_t)b * Sn * FS;
    float dxs[5], dys[5];
    #pragma unroll
    for (int j = 0; j < 4; j++) {
        int k = lane + 64 * j;
        dxs[j] = (float)(k % 17 - 8);
        dys[j] = (float)(k / 17 - 8);
    }
    {
        int k4 = (lane < Kwin - 256) ? 256 + lane : 256;
        dxs[4] = (float)(k4 % 17 - 8);
        dys[4] = (float)(k4 / 17 - 8);
    }
    float s4w = (lane < Kwin - 256) ? 1.0f : 0.0f;
    auto LIDX = [&](int s) { return (((size_t)b * Sn + s) * Pn + p) * 2; };
    if (typ == 0) {
        float px = locs[LIDX(0)], py = locs[LIDX(0) + 1];
        if (lane == 0) { nextPts[LIDX(0)] = px; nextPts[LIDX(0) + 1] = py; }
        for (int s = 0; s < 7; s++) {
            lk_track_fly(G + s * FS, G + (s + 1) * FS, px, py, dxs, dys, s4w);
            if (lane == 0) { nextPts[LIDX(s + 1)] = px; nextPts[LIDX(s + 1) + 1] = py; }
        }
        if (lane == 0) { fbackPts[LIDX(7)] = px; fbackPts[LIDX(7) + 1] = py; }
        for (int i = 0; i < 7; i++) {
            lk_track_fly(G + (7 - i) * FS, G + (6 - i) * FS, px, py, dxs, dys, s4w);
            if (lane == 0) { fbackPts[LIDX(6 - i)] = px; fbackPts[LIDX(6 - i) + 1] = py; }
        }
    } else {
        float px = locs[LIDX(7)], py = locs[LIDX(7) + 1];
        if (lane == 0) { backPts[LIDX(7)] = px; backPts[LIDX(7) + 1] = py; }
        for (int i = 0; i < 7; i++) {
            lk_track_fly(G + (7 - i) * FS, G + (6 - i) * FS, px, py, dxs, dys, s4w);
            if (lane == 0) { backPts[LIDX(6 - i)] = px; backPts[LIDX(6 - i) + 1] = py; }
        }
    }
}

// ---------------- launch ----------------
extern "C" void kernel_launch(void* const* d_in, const int* in_sizes, int n_in,
                              void* d_out, int out_size, void* d_ws, size_t ws_size,
                              hipStream_t stream) {
    const float* inputs = (const float*)d_in[0];
    const float* Wdet = (const float*)d_in[1];
    const float* bdet = (const float*)d_in[2];
    float* out = (float*)d_out;

    const size_t N_hm = (size_t)Bn * Sn * Pn * HD * WD;   // 8,912,896
    const size_t N_pts = (size_t)Bn * Sn * Pn * 2;        // 4352
    float* hm = out;
    float* locs = out + N_hm;
    float* scos = locs + N_pts;
    float* nextPts = scos + (size_t)Bn * Sn * Pn;
    float* fbackPts = nextPts + N_pts;
    float* backPts = fbackPts + N_pts;

    conv_kernel<<<NIMG * 64, 256, 0, stream>>>(inputs, Wdet, bdet, hm);
    smax_kernel<<<NIMG * Pn, 256, 0, stream>>>(hm, locs, scos);

    const size_t gray_elems = (size_t)NIMG * HWi;
    if (ws_size >= 2 * gray_elems * sizeof(float)) {
        float* gray = (float*)d_ws;
        float* sh = gray + gray_elems;
        gray2_kernel<<<(NIMG * HWi / 4 + 255) / 256, 256, 0, stream>>>(inputs, gray, sh);
        lk_pair_kernel<<<2 * Bn * Pn, 64, 0, stream>>>(gray, sh, locs, nextPts, fbackPts, backPts);
    } else {
        lk_fly_kernel<<<2 * Bn * Pn, 64, 0, stream>>>(inputs, locs, nextPts, fbackPts, backPts);
    }
}